// Round 9
// baseline (209.866 us; speedup 1.0000x reference)
//
#include <hip/hip_runtime.h>
#include <hip/hip_bf16.h>

#define NROW 1600
#define NEG  3200
#define ROWS_FLAT 25600
#define NSPLIT 25        // 25 x 128 = 3200 j's

using bf16x8 = __attribute__((ext_vector_type(8))) short;
using f32x4  = __attribute__((ext_vector_type(4))) float;

__device__ __forceinline__ float bf2f(unsigned v) { return __uint_as_float(v << 16); }
__device__ __forceinline__ ushort f2bf(float f) {
  __hip_bfloat16 h = __float2bfloat16(f);
  return *(ushort*)&h;
}
__device__ __forceinline__ float load1(const ushort* p, size_t idx, int f32) {
  return f32 ? ((const float*)p)[idx] : bf2f(p[idx]);
}
// load 8 elements starting at element idx, as bf16x8 (converting if fp32)
__device__ __forceinline__ bf16x8 load8bf(const ushort* p, size_t idx, int f32) {
  if (!f32) return *(const bf16x8*)(p + idx);
  const float* q = (const float*)p;
  float4 a = *(const float4*)(q + idx);
  float4 b = *(const float4*)(q + idx + 4);
  uint4 u;
  u.x = (unsigned)f2bf(a.x) | ((unsigned)f2bf(a.y) << 16);
  u.y = (unsigned)f2bf(a.z) | ((unsigned)f2bf(a.w) << 16);
  u.z = (unsigned)f2bf(b.x) | ((unsigned)f2bf(b.y) << 16);
  u.w = (unsigned)f2bf(b.z) | ((unsigned)f2bf(b.w) << 16);
  return *(bf16x8*)&u;
}
// wave-level dtype sniff: 1 = fp32, 0 = bf16. Reads ushorts 0..127 of buffer.
__device__ __forceinline__ int sniff_f32(const ushort* p, int lane) {
  unsigned e = ((unsigned)p[2*lane] >> 7) & 0xffu;
  unsigned long long b = __ballot(e >= 100u && e <= 140u);
  return (__popcll(b) >= 40) ? 0 : 1;
}

// ---------------- K0: Wt[n][k] = bf16(W[k][n]) + zero accumulators ----------------
__global__ __launch_bounds__(256) void k_prepw(const ushort* __restrict__ W,
    ushort* __restrict__ Wt, int* __restrict__ zbase) {
  if (blockIdx.x == 0 && threadIdx.x < 21) zbase[threadIdx.x] = 0;  // wsum[4]+cnt[16]+done[1]
  int fW = sniff_f32(W, threadIdx.x & 63);
  int n = blockIdx.x, k = threadIdx.x;
  Wt[n*256 + k] = f2bf(load1(W, (size_t)k*256 + n, fW));
}

// ---------------- K1: MFMA projection + L2 normalize (no LDS staging) ----------------
// Block: 64 rows x 256 cols; wave w owns cols w*64..w*64+63 (4 b-frags),
// all 64 rows (4 a-frags read DIRECTLY from global, L2-served). Double-buffered.
__global__ __launch_bounds__(256) void k_proj(const ushort* __restrict__ fe0,
    const ushort* __restrict__ fe1, const ushort* __restrict__ Wt,
    const ushort* __restrict__ bias, ushort* __restrict__ Pb) {
  __shared__ ushort shc[4][32*72];   // 18.4 KB per-half epilogue buffer (stride 72)
  __shared__ float s_ss[4][64];
  const int tid = threadIdx.x;
  const int w = tid >> 6, lane = tid & 63, q = lane >> 4, m = lane & 15;
  const int grow0 = blockIdx.x * 64;
  const int src1 = (grow0 >= ROWS_FLAT);
  const ushort* src = src1 ? fe1 : fe0;
  const size_t rbase = (size_t)(src1 ? grow0 - ROWS_FLAT : grow0) * 256;
  const int fSrc = sniff_f32(src, lane);
  const int fB   = sniff_f32(bias, lane);
  // acc[mt][nt]: rows mt*16+(4q+reg), cols w*64+nt*16+m ; init with bias
  f32x4 acc[4][4];
  #pragma unroll
  for (int nt = 0; nt < 4; nt++) {
    float bb = load1(bias, w*64 + nt*16 + m, fB);
    f32x4 v = {bb, bb, bb, bb};
    #pragma unroll
    for (int mt = 0; mt < 4; mt++) acc[mt][nt] = v;
  }
  const ushort* wbase = Wt + (size_t)(w*64 + m)*256 + q*8;
  const size_t abase = rbase + (size_t)m*256 + q*8;   // + mt*16*256 + k0
  // software-pipelined k-loop: global A (L2) + global B (L2), no barriers
  bf16x8 a_cur[4], b_cur[4];
  #pragma unroll
  for (int mt = 0; mt < 4; mt++)
    a_cur[mt] = load8bf(src, abase + (size_t)mt*16*256, fSrc);
  #pragma unroll
  for (int nt = 0; nt < 4; nt++)
    b_cur[nt] = *(const bf16x8*)(wbase + (size_t)nt*16*256);
  #pragma unroll
  for (int k = 0; k < 8; k++) {
    bf16x8 a_nxt[4], b_nxt[4];
    if (k < 7) {
      int k0 = (k + 1) * 32;
      #pragma unroll
      for (int nt = 0; nt < 4; nt++)
        b_nxt[nt] = *(const bf16x8*)(wbase + (size_t)nt*16*256 + k0);
      #pragma unroll
      for (int mt = 0; mt < 4; mt++)
        a_nxt[mt] = load8bf(src, abase + (size_t)mt*16*256 + k0, fSrc);
    }
    #pragma unroll
    for (int nt = 0; nt < 4; nt++)
      #pragma unroll
      for (int mt = 0; mt < 4; mt++)
        acc[mt][nt] = __builtin_amdgcn_mfma_f32_16x16x32_bf16(a_cur[mt], b_cur[nt], acc[mt][nt], 0, 0, 0);
    if (k < 7) {
      #pragma unroll
      for (int x = 0; x < 4; x++) { a_cur[x] = a_nxt[x]; b_cur[x] = b_nxt[x]; }
    }
  }
  // cross-wave row-norm: partial ss per (mt,reg) over this wave's 64 cols
  float ssp[4][4];
  #pragma unroll
  for (int mt = 0; mt < 4; mt++)
    #pragma unroll
    for (int reg = 0; reg < 4; reg++) {
      float s = 0.f;
      #pragma unroll
      for (int nt = 0; nt < 4; nt++) { float v = acc[mt][nt][reg]; s += v*v; }
      ssp[mt][reg] = s;
    }
  #pragma unroll
  for (int mk = 1; mk < 16; mk <<= 1)
    #pragma unroll
    for (int mt = 0; mt < 4; mt++)
      #pragma unroll
      for (int reg = 0; reg < 4; reg++) ssp[mt][reg] += __shfl_xor(ssp[mt][reg], mk, 64);
  if (m == 0)
    #pragma unroll
    for (int mt = 0; mt < 4; mt++)
      #pragma unroll
      for (int reg = 0; reg < 4; reg++) s_ss[w][mt*16 + 4*q + reg] = ssp[mt][reg];
  __syncthreads();
  float inv[4][4];
  #pragma unroll
  for (int mt = 0; mt < 4; mt++)
    #pragma unroll
    for (int reg = 0; reg < 4; reg++) {
      int row = mt*16 + 4*q + reg;
      float s = s_ss[0][row] + s_ss[1][row] + s_ss[2][row] + s_ss[3][row];
      inv[mt][reg] = 1.0f / sqrtf(s);
    }
  // two 32-row halves: park bf16 in wave-private c-buf, then vector stores
  #pragma unroll
  for (int half = 0; half < 2; half++) {
    #pragma unroll
    for (int mt = half*2; mt < half*2 + 2; mt++)
      #pragma unroll
      for (int reg = 0; reg < 4; reg++) {
        int rl = (mt - half*2)*16 + 4*q + reg;
        #pragma unroll
        for (int nt = 0; nt < 4; nt++)
          shc[w][rl*72 + nt*16 + m] = f2bf(acc[mt][nt][reg] * inv[mt][reg]);
      }
    int rl = (lane >> 3), c16 = lane & 7;    // 8 rows x 8 col-chunks per iter
    #pragma unroll
    for (int it = 0; it < 4; it++) {
      int row = it*8 + rl;
      int grow = grow0 + half*32 + row;
      int srcid = grow / ROWS_FLAT;
      int rem   = grow % ROWS_FLAT;
      int b  = rem / 1600;
      int t  = (rem / 100) & 15;
      int qq = rem % 100;
      size_t orow = ((size_t)(srcid*1600 + b*100 + qq) * 16 + t) * 256;
      uint4 v = *(uint4*)&shc[w][row*72 + c16*8];
      *(uint4*)(Pb + orow + w*64 + c16*8) = v;
    }
  }
}

// ---------------- K2: bridge prep (Ab bf16), numer, softplus, bucketing ----------------
__global__ __launch_bounds__(256) void k_bridge(const ushort* __restrict__ Pb,
    const int* __restrict__ bridge, ushort* __restrict__ Ab,
    float* __restrict__ prm, float* __restrict__ numer,
    int* __restrict__ cnt, int* __restrict__ lst, float* __restrict__ wsum) {
  int i = blockIdx.x, c = threadIdx.x;
  int bh = bridge[i*3+0], bp = bridge[i*3+1], bt = bridge[i*3+2];
  float bhf = (float)bh, bpf = (float)bp, btf = (float)bt;
  float alpha = (bpf - bhf) / (btf - bhf);
  float sigma = alpha * (btf - bpf);
  const ushort* base = Pb + (size_t)i * 16 * 256;
  float g0 = bf2f(base[bh*256 + c]), g1 = bf2f(base[bp*256 + c]), g2 = bf2f(base[bt*256 + c]);
  float head = bf2f(base[c]), tail = bf2f(base[15*256 + c]);
  float a = (1.0f - alpha) * g0 + alpha * g2;
  float x = g1 - a;
  Ab[(size_t)i*256 + c] = f2bf(a);
  float xx = x*x, aac = a*a, sc = head*tail;
  #pragma unroll
  for (int mk = 1; mk < 64; mk <<= 1) {
    xx  += __shfl_xor(xx, mk, 64);
    aac += __shfl_xor(aac, mk, 64);
    sc  += __shfl_xor(sc, mk, 64);
  }
  __shared__ float red[3][4];
  int wv = c >> 6;
  if ((c & 63) == 0) { red[0][wv]=xx; red[1][wv]=aac; red[2][wv]=sc; }
  __syncthreads();
  if (c == 0) {
    float XX = red[0][0]+red[0][1]+red[0][2]+red[0][3];
    float AA = red[1][0]+red[1][1]+red[1][2]+red[1][3];
    float SC = red[2][0]+red[2][1]+red[2][2]+red[2][3];
    float inv2s2 = 1.0f / (2.0f * sigma * sigma);
    prm[i*2+0] = inv2s2;
    prm[i*2+1] = AA;
    numer[i] = expf(-XX * inv2s2);
    float sp = log1pf(expf(0.3f - SC));
    atomicAdd(wsum + 1, sp * (1.0f / 1600.0f));
    int pos = atomicAdd(cnt + bp, 1);
    lst[bp * 1600 + pos] = i;
  }
}

// ---------------- top-5 helpers ----------------
__device__ __forceinline__ void sort5(float* c) {
  #define CE(i,j) { float hi = fmaxf(c[i], c[j]), lo = fminf(c[i], c[j]); c[i]=hi; c[j]=lo; }
  CE(0,1) CE(3,4) CE(2,4) CE(2,3) CE(1,4) CE(0,3) CE(0,2) CE(1,3) CE(1,2)
  #undef CE
}
__device__ __forceinline__ void ins5(float* t, float v) {
  float hi, lo;
  hi = fmaxf(t[0], v); lo = fminf(t[0], v); t[0] = hi; v = lo;
  hi = fmaxf(t[1], v); lo = fminf(t[1], v); t[1] = hi; v = lo;
  hi = fmaxf(t[2], v); lo = fminf(t[2], v); t[2] = hi; v = lo;
  hi = fmaxf(t[3], v); lo = fminf(t[3], v); t[3] = hi; v = lo;
  t[4] = fmaxf(t[4], v);
}

// ---------------- K3: fused dist + per-split top-5 (64 i's/block, pipelined) ----------------
__global__ __launch_bounds__(256) void k_cross(const ushort* __restrict__ Pb,
    const ushort* __restrict__ Ab, const float* __restrict__ prm,
    const int* __restrict__ cnt, const int* __restrict__ lst,
    float* __restrict__ part) {
  int t = blockIdx.z;
  int n_t = min(cnt[t], 1600);
  int i0 = blockIdx.y * 64;
  if (i0 >= n_t) return;
  int j0 = blockIdx.x * 128;
  __shared__ int s_gis[64];
  __shared__ float s_red[4][64][6];
  int tid = threadIdx.x;
  if (tid < 64) {
    int gi = lst[t*1600 + min(i0 + tid, n_t - 1)];
    s_gis[tid] = min(max(gi, 0), NROW - 1);
  }
  __syncthreads();
  const int w = tid >> 6, lane = tid & 63, q = lane >> 4, m = lane & 15;
  const ushort* jp0 = Pb + ((size_t)(j0 + w*32 + m)*16 + t) * 256 + q*8;
  const ushort* jp1 = jp0 + (size_t)16*16*256;
  int gi[4];
  const ushort* ip[4];
  #pragma unroll
  for (int it = 0; it < 4; it++) {
    gi[it] = s_gis[it*16 + m];
    ip[it] = Ab + (size_t)gi[it] * 256 + q*8;
  }
  f32x4 acc[2][4];   // [jt][it]
  #pragma unroll
  for (int jt = 0; jt < 2; jt++)
    #pragma unroll
    for (int it = 0; it < 4; it++) { f32x4 z = {0.f,0.f,0.f,0.f}; acc[jt][it] = z; }
  // pipelined: prefetch k+1 while MFMA-ing k
  bf16x8 jc0 = *(const bf16x8*)(jp0);
  bf16x8 jc1 = *(const bf16x8*)(jp1);
  bf16x8 ic[4];
  #pragma unroll
  for (int it = 0; it < 4; it++) ic[it] = *(const bf16x8*)(ip[it]);
  #pragma unroll
  for (int k = 0; k < 8; k++) {
    bf16x8 jn0, jn1, in[4];
    if (k < 7) {
      int o = (k + 1) * 32;
      jn0 = *(const bf16x8*)(jp0 + o);
      jn1 = *(const bf16x8*)(jp1 + o);
      #pragma unroll
      for (int it = 0; it < 4; it++) in[it] = *(const bf16x8*)(ip[it] + o);
    }
    #pragma unroll
    for (int it = 0; it < 4; it++) {
      acc[0][it] = __builtin_amdgcn_mfma_f32_16x16x32_bf16(jc0, ic[it], acc[0][it], 0, 0, 0);
      acc[1][it] = __builtin_amdgcn_mfma_f32_16x16x32_bf16(jc1, ic[it], acc[1][it], 0, 0, 0);
    }
    if (k < 7) { jc0 = jn0; jc1 = jn1;
      #pragma unroll
      for (int it = 0; it < 4; it++) ic[it] = in[it];
    }
  }
  // per-lane top5/self per it-column. D: row(j) = 4q+reg (+jt*16), col(i) = m.
  float top[4][5], selfv[4];
  float pi[4], pa[4];
  #pragma unroll
  for (int it = 0; it < 4; it++) {
    pi[it] = prm[gi[it]*2]; pa[it] = prm[gi[it]*2+1];
    selfv[it] = -1e30f;
    #pragma unroll
    for (int k = 0; k < 5; k++) top[it][k] = -1e30f;
  }
  #pragma unroll
  for (int jt = 0; jt < 2; jt++)
    #pragma unroll
    for (int reg = 0; reg < 4; reg++) {
      int j = j0 + w*32 + jt*16 + 4*q + reg;
      #pragma unroll
      for (int it = 0; it < 4; it++) {
        float d = -(1.0f - 2.0f*acc[jt][it][reg] + pa[it]) * pi[it];
        if (j == gi[it]) selfv[it] = d; else ins5(top[it], d);
      }
    }
  // reduce over q (lane bits 4,5): bitonic 5-merge + self max
  #pragma unroll
  for (int mk = 16; mk <= 32; mk <<= 1) {
    #pragma unroll
    for (int it = 0; it < 4; it++) {
      float o[5], c[5];
      #pragma unroll
      for (int k = 0; k < 5; k++) o[k] = __shfl_xor(top[it][k], mk, 64);
      #pragma unroll
      for (int k = 0; k < 5; k++) c[k] = fmaxf(top[it][k], o[4 - k]);
      sort5(c);
      #pragma unroll
      for (int k = 0; k < 5; k++) top[it][k] = c[k];
      selfv[it] = fmaxf(selfv[it], __shfl_xor(selfv[it], mk, 64));
    }
  }
  if (q == 0) {
    #pragma unroll
    for (int it = 0; it < 4; it++) {
      #pragma unroll
      for (int k = 0; k < 5; k++) s_red[w][it*16 + m][k] = top[it][k];
      s_red[w][it*16 + m][5] = selfv[it];
    }
  }
  __syncthreads();
  if (tid < 64 && i0 + tid < n_t) {
    float T[5], S = s_red[0][tid][5];
    #pragma unroll
    for (int k = 0; k < 5; k++) T[k] = s_red[0][tid][k];
    #pragma unroll
    for (int w2 = 1; w2 < 4; w2++) {
      #pragma unroll
      for (int k = 0; k < 5; k++) ins5(T, s_red[w2][tid][k]);
      S = fmaxf(S, s_red[w2][tid][5]);
    }
    float* pp = part + ((size_t)s_gis[tid]*NSPLIT + blockIdx.x) * 6;
    #pragma unroll
    for (int k = 0; k < 5; k++) pp[k] = T[k];
    pp[5] = S;
  }
}

// ---------------- K4: parallel merge + last-block output write ----------------
__global__ __launch_bounds__(64) void k_merge(const float* __restrict__ part,
    const float* __restrict__ numer, float* __restrict__ wsum, int* __restrict__ done,
    const ushort* __restrict__ fe0, void* __restrict__ out) {
  int i = blockIdx.x * 64 + threadIdx.x;     // 25 blocks x 64 = 1600
  const float* pp = part + (size_t)i * NSPLIT * 6;
  float T[5]; float S = pp[5];
  #pragma unroll
  for (int k = 0; k < 5; k++) T[k] = pp[k];
  #pragma unroll
  for (int s = 1; s < NSPLIT; s++) {
    const float* ps = pp + s*6;
    float v0 = ps[0], v1 = ps[1], v2 = ps[2], v3 = ps[3], v4 = ps[4], v5 = ps[5];
    ins5(T, v0); ins5(T, v1); ins5(T, v2); ins5(T, v3); ins5(T, v4);
    S = fmaxf(S, v5);
  }
  float deno = expf(S);
  #pragma unroll
  for (int k = 0; k < 5; k++) deno += expf(T[k]);
  float local = numer[i] / deno;
  #pragma unroll
  for (int mk = 1; mk < 64; mk <<= 1) local += __shfl_xor(local, mk, 64);
  __shared__ int s_last;
  if (threadIdx.x == 0) {
    atomicAdd(wsum + 0, local * (1.0f / 1600.0f));
    __threadfence();
    s_last = (atomicAdd(done, 1) == 24);
  }
  __syncthreads();
  if (s_last) {
    int f = sniff_f32(fe0, threadIdx.x);
    if (threadIdx.x == 0) {
      __threadfence();
      float brown = __hip_atomic_load(wsum + 0, __ATOMIC_RELAXED, __HIP_MEMORY_SCOPE_AGENT);
      float sp    = __hip_atomic_load(wsum + 1, __ATOMIC_RELAXED, __HIP_MEMORY_SCOPE_AGENT);
      if (f) {
        ((float*)out)[0] = brown;
        ((float*)out)[1] = sp;
      } else {
        ushort* o = (ushort*)out;
        o[0] = f2bf(brown);
        o[1] = f2bf(sp);
      }
    }
  }
}

extern "C" void kernel_launch(void* const* d_in, const int* in_sizes, int n_in,
                              void* d_out, int out_size, void* d_ws, size_t ws_size,
                              hipStream_t stream) {
  const ushort* fe0    = (const ushort*)d_in[0];
  const ushort* fe1    = (const ushort*)d_in[1];
  const ushort* W      = (const ushort*)d_in[2];
  const ushort* bias   = (const ushort*)d_in[3];
  const int*    bridge = (const int*)d_in[4];

  // workspace (~28.2 MB)
  ushort* Pb    = (ushort*)d_ws;               // 13,107,200
  ushort* Ab    = Pb + 13107200;               // 409,600
  ushort* Wt    = Ab + 409600;                 // 65,536
  float*  part  = (float*)(Wt + 65536);        // 1600*25*6 = 240,000
  float*  prm   = part + 240000;               // 3,200
  float*  numer = prm + 3200;                  // 1,600
  float*  wsum  = numer + 1600;                // 4 floats
  int*    cnt   = (int*)(wsum + 4);            // 16
  int*    done  = cnt + 16;                    // 1
  int*    lst   = done + 1;                    // 25,600

  k_prepw <<<256, 256, 0, stream>>>(W, Wt, (int*)wsum);   // also zeroes wsum/cnt/done
  k_proj  <<<800, 256, 0, stream>>>(fe0, fe1, Wt, bias, Pb);
  k_bridge<<<1600, 256, 0, stream>>>(Pb, bridge, Ab, prm, numer, cnt, lst, wsum);
  k_cross <<<dim3(NSPLIT, 7, 16), 256, 0, stream>>>(Pb, Ab, prm, cnt, lst, part);
  k_merge <<<25, 64, 0, stream>>>(part, numer, wsum, done, fe0, d_out);
}

// Round 10
// 191.200 us; speedup vs baseline: 1.0976x; 1.0976x over previous
//
#include <hip/hip_runtime.h>
#include <hip/hip_bf16.h>

#define NROW 1600
#define NEG  3200
#define ROWS_FLAT 25600
#define NSPLIT 25        // 25 x 128 = 3200 j's

using bf16x8 = __attribute__((ext_vector_type(8))) short;
using f32x4  = __attribute__((ext_vector_type(4))) float;

__device__ __forceinline__ float bf2f(unsigned v) { return __uint_as_float(v << 16); }
__device__ __forceinline__ ushort f2bf(float f) {
  __hip_bfloat16 h = __float2bfloat16(f);
  return *(ushort*)&h;
}
__device__ __forceinline__ float load1(const ushort* p, size_t idx, int f32) {
  return f32 ? ((const float*)p)[idx] : bf2f(p[idx]);
}
__device__ __forceinline__ void load8(const ushort* p, size_t idx, int f32, float* o) {
  if (f32) {
    const float* q = (const float*)p;
    float4 a = *(const float4*)(q + idx);
    float4 b = *(const float4*)(q + idx + 4);
    o[0]=a.x; o[1]=a.y; o[2]=a.z; o[3]=a.w;
    o[4]=b.x; o[5]=b.y; o[6]=b.z; o[7]=b.w;
  } else {
    uint4 u = *(const uint4*)(p + idx);
    o[0]=bf2f(u.x & 0xffffu); o[1]=bf2f(u.x >> 16);
    o[2]=bf2f(u.y & 0xffffu); o[3]=bf2f(u.y >> 16);
    o[4]=bf2f(u.z & 0xffffu); o[5]=bf2f(u.z >> 16);
    o[6]=bf2f(u.w & 0xffffu); o[7]=bf2f(u.w >> 16);
  }
}
// wave-level dtype sniff: 1 = fp32, 0 = bf16. Reads ushorts 0..127 of buffer.
__device__ __forceinline__ int sniff_f32(const ushort* p, int lane) {
  unsigned e = ((unsigned)p[2*lane] >> 7) & 0xffu;
  unsigned long long b = __ballot(e >= 100u && e <= 140u);
  return (__popcll(b) >= 40) ? 0 : 1;
}

// ---------------- K0: Wt[n][k] = bf16(W[k][n]) + zero accumulators ----------------
__global__ __launch_bounds__(256) void k_prepw(const ushort* __restrict__ W,
    ushort* __restrict__ Wt, int* __restrict__ zbase) {
  if (blockIdx.x == 0 && threadIdx.x < 21) zbase[threadIdx.x] = 0;  // wsum[4]+cnt[16]+done[1]
  int fW = sniff_f32(W, threadIdx.x & 63);
  int n = blockIdx.x, k = threadIdx.x;
  Wt[n*256 + k] = f2bf(load1(W, (size_t)k*256 + n, fW));
}

// ---------------- K1: MFMA projection + L2 normalize ----------------
// Round-8 structure (LDS A-tile, XOR swizzle, pipelined k-loop) with async
// global_load_lds staging: HW writes lane l -> base + l*16B, so the swizzle is
// applied by permuting each lane's GLOBAL source chunk (kc = (l&31) ^ (r&7)).
__global__ __launch_bounds__(256) void k_proj(const ushort* __restrict__ fe0,
    const ushort* __restrict__ fe1, const ushort* __restrict__ Wt,
    const ushort* __restrict__ bias, ushort* __restrict__ Pb) {
  __shared__ union {
    ushort x[64*256];      // 32 KB swizzled A-tile: phys_k = k ^ ((r&7)<<3)
    ushort c[4][32*72];    // 18.4 KB per-half epilogue buffer (stride 72)
  } sh;
  __shared__ float s_ss[4][64];
  const int tid = threadIdx.x;
  const int w = tid >> 6, lane = tid & 63, q = lane >> 4, m = lane & 15;
  const int grow0 = blockIdx.x * 64;
  const int src1 = (grow0 >= ROWS_FLAT);
  const ushort* src = src1 ? fe1 : fe0;
  const size_t rbase = (size_t)(src1 ? grow0 - ROWS_FLAT : grow0) * 256;
  const int fSrc = sniff_f32(src, lane);
  const int fB   = sniff_f32(bias, lane);
  // stage 64 rows x 256 -> LDS (swizzled)
  if (!fSrc) {   // bf16: async direct-to-LDS, swizzle via permuted global source
    #pragma unroll
    for (int i = 0; i < 8; i++) {
      int c = w*8 + i;                    // chunk 0..31 -> rows 2c, 2c+1
      int r = 2*c + (lane >> 5);
      int kc = (lane & 31) ^ (r & 7);
      const ushort* gp = src + rbase + (size_t)r*256 + kc*8;
      __builtin_amdgcn_global_load_lds(
        (const __attribute__((address_space(1))) unsigned int*)gp,
        (__attribute__((address_space(3))) unsigned int*)&sh.x[c*512],
        16, 0, 0);
    }
  } else {       // fp32 convert path (VGPR staging)
    #pragma unroll
    for (int i = 0; i < 8; i++) {
      int l = tid + i*256;
      int r = l >> 5, kc = l & 31;
      float o[8];
      load8(src, rbase + (size_t)r*256 + kc*8, 1, o);
      uint4 u;
      u.x = (unsigned)f2bf(o[0]) | ((unsigned)f2bf(o[1]) << 16);
      u.y = (unsigned)f2bf(o[2]) | ((unsigned)f2bf(o[3]) << 16);
      u.z = (unsigned)f2bf(o[4]) | ((unsigned)f2bf(o[5]) << 16);
      u.w = (unsigned)f2bf(o[6]) | ((unsigned)f2bf(o[7]) << 16);
      *(uint4*)&sh.x[r*256 + ((kc*8) ^ ((r&7)<<3))] = u;
    }
  }
  __syncthreads();
  // acc[mt][nt]: rows mt*16+(4q+reg), cols w*64+nt*16+m ; init with bias
  f32x4 acc[4][4];
  #pragma unroll
  for (int nt = 0; nt < 4; nt++) {
    float bb = load1(bias, w*64 + nt*16 + m, fB);
    f32x4 v = {bb, bb, bb, bb};
    #pragma unroll
    for (int mt = 0; mt < 4; mt++) acc[mt][nt] = v;
  }
  const int sw = (m & 7) << 3;   // row swizzle (row = mt*16+m, (row&7)==(m&7))
  const ushort* wbase = Wt + (size_t)(w*64 + m)*256 + q*8;
  // software-pipelined k-loop: prefetch k+1 fragments before k's MFMAs
  bf16x8 a_cur[4], b_cur[4];
  #pragma unroll
  for (int mt = 0; mt < 4; mt++)
    a_cur[mt] = *(const bf16x8*)&sh.x[(mt*16 + m)*256 + ((q*8) ^ sw)];
  #pragma unroll
  for (int nt = 0; nt < 4; nt++)
    b_cur[nt] = *(const bf16x8*)(wbase + (size_t)nt*16*256);
  #pragma unroll
  for (int k = 0; k < 8; k++) {
    bf16x8 a_nxt[4], b_nxt[4];
    if (k < 7) {
      int k0 = (k + 1) * 32;
      #pragma unroll
      for (int nt = 0; nt < 4; nt++)
        b_nxt[nt] = *(const bf16x8*)(wbase + (size_t)nt*16*256 + k0);
      int pk = (k0 + q*8) ^ sw;
      #pragma unroll
      for (int mt = 0; mt < 4; mt++)
        a_nxt[mt] = *(const bf16x8*)&sh.x[(mt*16 + m)*256 + pk];
    }
    #pragma unroll
    for (int nt = 0; nt < 4; nt++)
      #pragma unroll
      for (int mt = 0; mt < 4; mt++)
        acc[mt][nt] = __builtin_amdgcn_mfma_f32_16x16x32_bf16(a_cur[mt], b_cur[nt], acc[mt][nt], 0, 0, 0);
    if (k < 7) {
      #pragma unroll
      for (int x = 0; x < 4; x++) { a_cur[x] = a_nxt[x]; b_cur[x] = b_nxt[x]; }
    }
  }
  // cross-wave row-norm: partial ss per (mt,reg) over this wave's 64 cols
  float ssp[4][4];
  #pragma unroll
  for (int mt = 0; mt < 4; mt++)
    #pragma unroll
    for (int reg = 0; reg < 4; reg++) {
      float s = 0.f;
      #pragma unroll
      for (int nt = 0; nt < 4; nt++) { float v = acc[mt][nt][reg]; s += v*v; }
      ssp[mt][reg] = s;
    }
  #pragma unroll
  for (int mk = 1; mk < 16; mk <<= 1)
    #pragma unroll
    for (int mt = 0; mt < 4; mt++)
      #pragma unroll
      for (int reg = 0; reg < 4; reg++) ssp[mt][reg] += __shfl_xor(ssp[mt][reg], mk, 64);
  if (m == 0)
    #pragma unroll
    for (int mt = 0; mt < 4; mt++)
      #pragma unroll
      for (int reg = 0; reg < 4; reg++) s_ss[w][mt*16 + 4*q + reg] = ssp[mt][reg];
  __syncthreads();   // also retires A-tile before c-overlay
  float inv[4][4];
  #pragma unroll
  for (int mt = 0; mt < 4; mt++)
    #pragma unroll
    for (int reg = 0; reg < 4; reg++) {
      int row = mt*16 + 4*q + reg;
      float s = s_ss[0][row] + s_ss[1][row] + s_ss[2][row] + s_ss[3][row];
      inv[mt][reg] = 1.0f / sqrtf(s);
    }
  // two 32-row halves: park bf16 in wave-private c-buf, then vector stores
  #pragma unroll
  for (int half = 0; half < 2; half++) {
    #pragma unroll
    for (int mt = half*2; mt < half*2 + 2; mt++)
      #pragma unroll
      for (int reg = 0; reg < 4; reg++) {
        int rl = (mt - half*2)*16 + 4*q + reg;
        #pragma unroll
        for (int nt = 0; nt < 4; nt++)
          sh.c[w][rl*72 + nt*16 + m] = f2bf(acc[mt][nt][reg] * inv[mt][reg]);
      }
    int rl = (lane >> 3), c16 = lane & 7;    // 8 rows x 8 col-chunks per iter
    #pragma unroll
    for (int it = 0; it < 4; it++) {
      int row = it*8 + rl;
      int grow = grow0 + half*32 + row;
      int srcid = grow / ROWS_FLAT;
      int rem   = grow % ROWS_FLAT;
      int b  = rem / 1600;
      int t  = (rem / 100) & 15;
      int qq = rem % 100;
      size_t orow = ((size_t)(srcid*1600 + b*100 + qq) * 16 + t) * 256;
      uint4 v = *(uint4*)&sh.c[w][row*72 + c16*8];
      *(uint4*)(Pb + orow + w*64 + c16*8) = v;
    }
  }
}

// ---------------- K2: bridge prep (Ab bf16), numer, softplus, bucketing ----------------
__global__ __launch_bounds__(256) void k_bridge(const ushort* __restrict__ Pb,
    const int* __restrict__ bridge, ushort* __restrict__ Ab,
    float* __restrict__ prm, float* __restrict__ numer,
    int* __restrict__ cnt, int* __restrict__ lst, float* __restrict__ wsum) {
  int i = blockIdx.x, c = threadIdx.x;
  int bh = bridge[i*3+0], bp = bridge[i*3+1], bt = bridge[i*3+2];
  float bhf = (float)bh, bpf = (float)bp, btf = (float)bt;
  float alpha = (bpf - bhf) / (btf - bhf);
  float sigma = alpha * (btf - bpf);
  const ushort* base = Pb + (size_t)i * 16 * 256;
  float g0 = bf2f(base[bh*256 + c]), g1 = bf2f(base[bp*256 + c]), g2 = bf2f(base[bt*256 + c]);
  float head = bf2f(base[c]), tail = bf2f(base[15*256 + c]);
  float a = (1.0f - alpha) * g0 + alpha * g2;
  float x = g1 - a;
  Ab[(size_t)i*256 + c] = f2bf(a);
  float xx = x*x, aac = a*a, sc = head*tail;
  #pragma unroll
  for (int mk = 1; mk < 64; mk <<= 1) {
    xx  += __shfl_xor(xx, mk, 64);
    aac += __shfl_xor(aac, mk, 64);
    sc  += __shfl_xor(sc, mk, 64);
  }
  __shared__ float red[3][4];
  int wv = c >> 6;
  if ((c & 63) == 0) { red[0][wv]=xx; red[1][wv]=aac; red[2][wv]=sc; }
  __syncthreads();
  if (c == 0) {
    float XX = red[0][0]+red[0][1]+red[0][2]+red[0][3];
    float AA = red[1][0]+red[1][1]+red[1][2]+red[1][3];
    float SC = red[2][0]+red[2][1]+red[2][2]+red[2][3];
    float inv2s2 = 1.0f / (2.0f * sigma * sigma);
    prm[i*2+0] = inv2s2;
    prm[i*2+1] = AA;
    numer[i] = expf(-XX * inv2s2);
    float sp = log1pf(expf(0.3f - SC));
    atomicAdd(wsum + 1, sp * (1.0f / 1600.0f));
    int pos = atomicAdd(cnt + bp, 1);
    lst[bp * 1600 + pos] = i;
  }
}

// ---------------- top-5 helpers ----------------
__device__ __forceinline__ void sort5(float* c) {
  #define CE(i,j) { float hi = fmaxf(c[i], c[j]), lo = fminf(c[i], c[j]); c[i]=hi; c[j]=lo; }
  CE(0,1) CE(3,4) CE(2,4) CE(2,3) CE(1,4) CE(0,3) CE(0,2) CE(1,3) CE(1,2)
  #undef CE
}
__device__ __forceinline__ void ins5(float* t, float v) {
  float hi, lo;
  hi = fmaxf(t[0], v); lo = fminf(t[0], v); t[0] = hi; v = lo;
  hi = fmaxf(t[1], v); lo = fminf(t[1], v); t[1] = hi; v = lo;
  hi = fmaxf(t[2], v); lo = fminf(t[2], v); t[2] = hi; v = lo;
  hi = fmaxf(t[3], v); lo = fminf(t[3], v); t[3] = hi; v = lo;
  t[4] = fmaxf(t[4], v);
}

// ---------------- K3: fused dist + per-split top-5 (64 i's/block, pipelined) ----------------
__global__ __launch_bounds__(256) void k_cross(const ushort* __restrict__ Pb,
    const ushort* __restrict__ Ab, const float* __restrict__ prm,
    const int* __restrict__ cnt, const int* __restrict__ lst,
    float* __restrict__ part) {
  int t = blockIdx.z;
  int n_t = min(cnt[t], 1600);
  int i0 = blockIdx.y * 64;
  if (i0 >= n_t) return;
  int j0 = blockIdx.x * 128;
  __shared__ int s_gis[64];
  __shared__ float s_red[4][64][6];
  int tid = threadIdx.x;
  if (tid < 64) {
    int gi = lst[t*1600 + min(i0 + tid, n_t - 1)];
    s_gis[tid] = min(max(gi, 0), NROW - 1);
  }
  __syncthreads();
  const int w = tid >> 6, lane = tid & 63, q = lane >> 4, m = lane & 15;
  const ushort* jp0 = Pb + ((size_t)(j0 + w*32 + m)*16 + t) * 256 + q*8;
  const ushort* jp1 = jp0 + (size_t)16*16*256;
  int gi[4];
  const ushort* ip[4];
  #pragma unroll
  for (int it = 0; it < 4; it++) {
    gi[it] = s_gis[it*16 + m];
    ip[it] = Ab + (size_t)gi[it] * 256 + q*8;
  }
  f32x4 acc[2][4];   // [jt][it]
  #pragma unroll
  for (int jt = 0; jt < 2; jt++)
    #pragma unroll
    for (int it = 0; it < 4; it++) { f32x4 z = {0.f,0.f,0.f,0.f}; acc[jt][it] = z; }
  // pipelined: prefetch k+1 while MFMA-ing k
  bf16x8 jc0 = *(const bf16x8*)(jp0);
  bf16x8 jc1 = *(const bf16x8*)(jp1);
  bf16x8 ic[4];
  #pragma unroll
  for (int it = 0; it < 4; it++) ic[it] = *(const bf16x8*)(ip[it]);
  #pragma unroll
  for (int k = 0; k < 8; k++) {
    bf16x8 jn0, jn1, in[4];
    if (k < 7) {
      int o = (k + 1) * 32;
      jn0 = *(const bf16x8*)(jp0 + o);
      jn1 = *(const bf16x8*)(jp1 + o);
      #pragma unroll
      for (int it = 0; it < 4; it++) in[it] = *(const bf16x8*)(ip[it] + o);
    }
    #pragma unroll
    for (int it = 0; it < 4; it++) {
      acc[0][it] = __builtin_amdgcn_mfma_f32_16x16x32_bf16(jc0, ic[it], acc[0][it], 0, 0, 0);
      acc[1][it] = __builtin_amdgcn_mfma_f32_16x16x32_bf16(jc1, ic[it], acc[1][it], 0, 0, 0);
    }
    if (k < 7) { jc0 = jn0; jc1 = jn1;
      #pragma unroll
      for (int it = 0; it < 4; it++) ic[it] = in[it];
    }
  }
  // per-lane top5/self per it-column. D: row(j) = 4q+reg (+jt*16), col(i) = m.
  float top[4][5], selfv[4];
  float pi[4], pa[4];
  #pragma unroll
  for (int it = 0; it < 4; it++) {
    pi[it] = prm[gi[it]*2]; pa[it] = prm[gi[it]*2+1];
    selfv[it] = -1e30f;
    #pragma unroll
    for (int k = 0; k < 5; k++) top[it][k] = -1e30f;
  }
  #pragma unroll
  for (int jt = 0; jt < 2; jt++)
    #pragma unroll
    for (int reg = 0; reg < 4; reg++) {
      int j = j0 + w*32 + jt*16 + 4*q + reg;
      #pragma unroll
      for (int it = 0; it < 4; it++) {
        float d = -(1.0f - 2.0f*acc[jt][it][reg] + pa[it]) * pi[it];
        if (j == gi[it]) selfv[it] = d; else ins5(top[it], d);
      }
    }
  // reduce over q (lane bits 4,5): bitonic 5-merge + self max
  #pragma unroll
  for (int mk = 16; mk <= 32; mk <<= 1) {
    #pragma unroll
    for (int it = 0; it < 4; it++) {
      float o[5], c[5];
      #pragma unroll
      for (int k = 0; k < 5; k++) o[k] = __shfl_xor(top[it][k], mk, 64);
      #pragma unroll
      for (int k = 0; k < 5; k++) c[k] = fmaxf(top[it][k], o[4 - k]);
      sort5(c);
      #pragma unroll
      for (int k = 0; k < 5; k++) top[it][k] = c[k];
      selfv[it] = fmaxf(selfv[it], __shfl_xor(selfv[it], mk, 64));
    }
  }
  if (q == 0) {
    #pragma unroll
    for (int it = 0; it < 4; it++) {
      #pragma unroll
      for (int k = 0; k < 5; k++) s_red[w][it*16 + m][k] = top[it][k];
      s_red[w][it*16 + m][5] = selfv[it];
    }
  }
  __syncthreads();
  if (tid < 64 && i0 + tid < n_t) {
    float T[5], S = s_red[0][tid][5];
    #pragma unroll
    for (int k = 0; k < 5; k++) T[k] = s_red[0][tid][k];
    #pragma unroll
    for (int w2 = 1; w2 < 4; w2++) {
      #pragma unroll
      for (int k = 0; k < 5; k++) ins5(T, s_red[w2][tid][k]);
      S = fmaxf(S, s_red[w2][tid][5]);
    }
    float* pp = part + ((size_t)s_gis[tid]*NSPLIT + blockIdx.x) * 6;
    #pragma unroll
    for (int k = 0; k < 5; k++) pp[k] = T[k];
    pp[5] = S;
  }
}

// ---------------- K4: parallel merge + last-block output write ----------------
__global__ __launch_bounds__(64) void k_merge(const float* __restrict__ part,
    const float* __restrict__ numer, float* __restrict__ wsum, int* __restrict__ done,
    const ushort* __restrict__ fe0, void* __restrict__ out) {
  int i = blockIdx.x * 64 + threadIdx.x;     // 25 blocks x 64 = 1600
  const float* pp = part + (size_t)i * NSPLIT * 6;
  float T[5]; float S = pp[5];
  #pragma unroll
  for (int k = 0; k < 5; k++) T[k] = pp[k];
  #pragma unroll
  for (int s = 1; s < NSPLIT; s++) {
    const float* ps = pp + s*6;
    float v0 = ps[0], v1 = ps[1], v2 = ps[2], v3 = ps[3], v4 = ps[4], v5 = ps[5];
    ins5(T, v0); ins5(T, v1); ins5(T, v2); ins5(T, v3); ins5(T, v4);
    S = fmaxf(S, v5);
  }
  float deno = expf(S);
  #pragma unroll
  for (int k = 0; k < 5; k++) deno += expf(T[k]);
  float local = numer[i] / deno;
  #pragma unroll
  for (int mk = 1; mk < 64; mk <<= 1) local += __shfl_xor(local, mk, 64);
  __shared__ int s_last;
  if (threadIdx.x == 0) {
    atomicAdd(wsum + 0, local * (1.0f / 1600.0f));
    __threadfence();
    s_last = (atomicAdd(done, 1) == 24);
  }
  __syncthreads();
  if (s_last) {
    int f = sniff_f32(fe0, threadIdx.x);
    if (threadIdx.x == 0) {
      __threadfence();
      float brown = __hip_atomic_load(wsum + 0, __ATOMIC_RELAXED, __HIP_MEMORY_SCOPE_AGENT);
      float sp    = __hip_atomic_load(wsum + 1, __ATOMIC_RELAXED, __HIP_MEMORY_SCOPE_AGENT);
      if (f) {
        ((float*)out)[0] = brown;
        ((float*)out)[1] = sp;
      } else {
        ushort* o = (ushort*)out;
        o[0] = f2bf(brown);
        o[1] = f2bf(sp);
      }
    }
  }
}

extern "C" void kernel_launch(void* const* d_in, const int* in_sizes, int n_in,
                              void* d_out, int out_size, void* d_ws, size_t ws_size,
                              hipStream_t stream) {
  const ushort* fe0    = (const ushort*)d_in[0];
  const ushort* fe1    = (const ushort*)d_in[1];
  const ushort* W      = (const ushort*)d_in[2];
  const ushort* bias   = (const ushort*)d_in[3];
  const int*    bridge = (const int*)d_in[4];

  // workspace (~28.2 MB)
  ushort* Pb    = (ushort*)d_ws;               // 13,107,200
  ushort* Ab    = Pb + 13107200;               // 409,600
  ushort* Wt    = Ab + 409600;                 // 65,536
  float*  part  = (float*)(Wt + 65536);        // 1600*25*6 = 240,000
  float*  prm   = part + 240000;               // 3,200
  float*  numer = prm + 3200;                  // 1,600
  float*  wsum  = numer + 1600;                // 4 floats
  int*    cnt   = (int*)(wsum + 4);            // 16
  int*    done  = cnt + 16;                    // 1
  int*    lst   = done + 1;                    // 25,600

  k_prepw <<<256, 256, 0, stream>>>(W, Wt, (int*)wsum);   // also zeroes wsum/cnt/done
  k_proj  <<<800, 256, 0, stream>>>(fe0, fe1, Wt, bias, Pb);
  k_bridge<<<1600, 256, 0, stream>>>(Pb, bridge, Ab, prm, numer, cnt, lst, wsum);
  k_cross <<<dim3(NSPLIT, 7, 16), 256, 0, stream>>>(Pb, Ab, prm, cnt, lst, part);
  k_merge <<<25, 64, 0, stream>>>(part, numer, wsum, done, fe0, d_out);
}